// Round 1
// baseline (183.928 us; speedup 1.0000x reference)
//
#include <hip/hip_runtime.h>

// Axial 7x7 attention, fused. Shapes (fixed by reference):
//   N=512, GRID=7, Cq=64, Cv=512, B=N*7=3584
//   qH,qW: (B,7,64)  kH,kW: (B,64,7)  vH,vW: (B,512,7)
//   out: (N,512,7,7) fp32
// Memory-bound: 180 MB total traffic -> ~28.5us roofline @6.3TB/s.

#define NEGINF (-1e20f)

constexpr int QK_SLICE = 7 * 7 * 64;    // 3136 floats per n per q/k array
constexpr int V_SLICE  = 7 * 512 * 7;   // 25088 floats per n per v array / out

// LDS layout (floats):
//   union region U (14504 floats):
//     phase A/B:  qHs 49x68 (3332) | kHs 7x456 (3192) | qWs (3332) | kWs (3192)
//     phase D:    As 7x1036 (7252) | Bs 7x1036 (7252)   (v chunks, j padded 7->8)
//   P (784): 49 rows x stride 16, logits then probabilities
// total = 15288 floats = 61152 B < 64KB -> 2 blocks/CU (LDS-limited)

__global__ __launch_bounds__(512, 4) void fused_axial(
    const float* __restrict__ qH, const float* __restrict__ kH,
    const float* __restrict__ vH, const float* __restrict__ qW,
    const float* __restrict__ kW, const float* __restrict__ vW,
    float* __restrict__ out)
{
    __shared__ float sm[15288];
    float* U = sm;
    float* P = sm + 14504;

    const int n = blockIdx.x;
    const int t = threadIdx.x;

    float* qHs = U;
    float* kHs = U + 3332;
    float* qWs = U + 6524;
    float* kWs = U + 9856;

    // ---- Phase A: stage q/k slices (coalesced float4) ----
    {
        const float* srcQH = qH + n * QK_SLICE;
        const float* srcKH = kH + n * QK_SLICE;
        const float* srcQW = qW + n * QK_SLICE;
        const float* srcKW = kW + n * QK_SLICE;
        for (int it = t; it < 784; it += 512) {        // 784 float4 per array
            int wh = it >> 4;                          // q: flat = wh*64 + c
            int c  = (it & 15) << 2;
            float4 v0 = ((const float4*)srcQH)[it];
            *(float4*)(qHs + wh * 68 + c) = v0;
            float4 v1 = ((const float4*)srcQW)[it];
            *(float4*)(qWs + wh * 68 + c) = v1;
            int w = it / 112;                          // k: flat = w*448 + r
            int r = (it - w * 112) << 2;
            float4 v2 = ((const float4*)srcKH)[it];
            *(float4*)(kHs + w * 456 + r) = v2;
            float4 v3 = ((const float4*)srcKW)[it];
            *(float4*)(kWs + w * 456 + r) = v3;
        }
    }
    __syncthreads();

    // ---- Phase B: 686 dot products (len 64) -> logits in P ----
    for (int d = t; d < 686; d += 512) {
        const bool isH = d < 343;
        int dd = isH ? d : d - 343;
        int a   = dd / 49;            // H: w   W: h
        int rem = dd - a * 49;
        int b   = rem / 7;            // H: h   W: w
        int j   = rem - b * 7;
        const float* qrow  = (isH ? qHs : qWs) + (a * 7 + b) * 68;
        const float* kbase = (isH ? kHs : kWs) + a * 456 + j;
        float e = 0.f;
        #pragma unroll
        for (int c = 0; c < 64; c += 4) {
            float4 qv = *(const float4*)(qrow + c);
            e += qv.x * kbase[c * 7];
            e += qv.y * kbase[c * 7 + 7];
            e += qv.z * kbase[c * 7 + 14];
            e += qv.w * kbase[c * 7 + 21];
        }
        if (isH) {
            if (b == j) e = NEGINF;               // diagonal mask on eH(h==j)
            P[(b * 7 + a) * 16 + j] = e;          // logits[n,h,w,j]
        } else {
            P[(a * 7 + b) * 16 + 7 + j] = e;      // logits[n,h,w,7+y]
        }
    }
    __syncthreads();

    // ---- Phase C: softmax over 14 per (h,w) ----
    if (t < 49) {
        float* row = P + t * 16;
        float l[14];
        float m = -3.4e38f;
        #pragma unroll
        for (int k = 0; k < 14; ++k) { l[k] = row[k]; m = fmaxf(m, l[k]); }
        float s = 0.f;
        #pragma unroll
        for (int k = 0; k < 14; ++k) { l[k] = __expf(l[k] - m); s += l[k]; }
        float inv = 1.f / s;
        #pragma unroll
        for (int k = 0; k < 14; ++k) row[k] = l[k] * inv;
    }
    __syncthreads();

    // ---- Phase D: out[n,c,h,w] = sum_j p[hw][j]*vH[n,w,c,j] + p[hw][7+j]*vW[n,h,c,j]
    const int g  = t / 49;            // c-group (0..9 active, 10 = idle)
    const int hw = t - g * 49;
    const int h  = hw / 7;
    const int w  = hw - h * 7;
    const bool active = (t < 490);

    float pr[14];
    if (active) {
        #pragma unroll
        for (int k = 0; k < 14; ++k) pr[k] = P[hw * 16 + k];
    }

    float* As = U;                    // vH chunk: [w][c_local][8], stride 1036
    float* Bs = U + 7252;             // vW chunk: [h][c_local][8]
    float* outn = out + n * V_SLICE;
    const float* vHn = vH + n * V_SLICE;
    const float* vWn = vW + n * V_SLICE;

    for (int chunk = 0; chunk < 4; ++chunk) {
        const int c0 = chunk * 128;
        __syncthreads();              // previous compute done before overwrite
        // stage 2 arrays x 7 regions x 224 float4 (coalesced global float4)
        for (int it = t; it < 3136; it += 512) {
            int arr = it / 1568;
            int rem = it - arr * 1568;
            int i   = rem / 224;                  // region (w for vH, h for vW)
            int q4  = rem - i * 224;
            int r   = q4 << 2;                    // flat = c_local*7 + j
            const float* src = (arr == 0 ? vHn : vWn) + i * 3584 + c0 * 7 + r;
            float4 val = *(const float4*)src;
            float* dst = (arr == 0 ? As : Bs) + i * 1036;
            const float* vv = (const float*)&val;
            #pragma unroll
            for (int u = 0; u < 4; ++u) {
                int rr = r + u;
                int cl = rr / 7;
                int jj = rr - cl * 7;
                dst[cl * 8 + jj] = vv[u];
            }
        }
        __syncthreads();
        if (active) {
            #pragma unroll
            for (int i = 0; i < 13; ++i) {
                int cl = g + 10 * i;
                if (cl < 128) {
                    const float* arow = As + w * 1036 + cl * 8;
                    const float* brow = Bs + h * 1036 + cl * 8;
                    float4 a0 = *(const float4*)(arow);
                    float4 a1 = *(const float4*)(arow + 4);
                    float4 b0 = *(const float4*)(brow);
                    float4 b1 = *(const float4*)(brow + 4);
                    float acc;
                    acc  = pr[0] * a0.x + pr[1] * a0.y + pr[2] * a0.z + pr[3] * a0.w;
                    acc += pr[4] * a1.x + pr[5] * a1.y + pr[6] * a1.z;
                    acc += pr[7] * b0.x + pr[8] * b0.y + pr[9] * b0.z + pr[10] * b0.w;
                    acc += pr[11] * b1.x + pr[12] * b1.y + pr[13] * b1.z;
                    outn[(c0 + cl) * 49 + hw] = acc;   // contiguous per wave
                }
            }
        }
    }
}

extern "C" void kernel_launch(void* const* d_in, const int* in_sizes, int n_in,
                              void* d_out, int out_size, void* d_ws, size_t ws_size,
                              hipStream_t stream) {
    const float* qH = (const float*)d_in[0];
    const float* kH = (const float*)d_in[1];
    const float* vH = (const float*)d_in[2];
    const float* qW = (const float*)d_in[3];
    const float* kW = (const float*)d_in[4];
    const float* vW = (const float*)d_in[5];
    float* out = (float*)d_out;
    fused_axial<<<512, 512, 0, stream>>>(qH, kH, vH, qW, kW, vW, out);
}